// Round 7
// baseline (508.417 us; speedup 1.0000x reference)
//
#include <hip/hip_runtime.h>
#include <hip/hip_cooperative_groups.h>
#include <stdint.h>

namespace cg = cooperative_groups;

#define HW 4096
#define NC 512
#define NB 8

typedef __attribute__((ext_vector_type(8))) short short8;
typedef __attribute__((ext_vector_type(4))) float f32x4;

__device__ __forceinline__ unsigned short f2bf(float f) {
  unsigned int u = __builtin_bit_cast(unsigned int, f);
  unsigned int r = (u + 0x7FFFu + ((u >> 16) & 1u)) >> 16;
  return (unsigned short)r;
}
__device__ __forceinline__ float hsig(float v) {
  return fminf(fmaxf((v + 3.0f) * (1.0f / 6.0f), 0.0f), 1.0f);
}

__device__ __forceinline__ void gload16(const void* g, void* l) {
  __builtin_amdgcn_global_load_lds(
      (const __attribute__((address_space(1))) unsigned int*)g,
      (__attribute__((address_space(3))) unsigned int*)l, 16, 0, 0);
}

// Full-wave (64-lane) sum reduce.
__device__ __forceinline__ float wave_reduce(float p) {
#pragma unroll
  for (int m = 1; m < 64; m <<= 1) p += __shfl_xor(p, m);
  return p;
}

// 256-thread (4-wave) block reductions.
__device__ __forceinline__ float block_reduce_sum(float v, volatile float* red) {
  int t = threadIdx.x;
#pragma unroll
  for (int m = 1; m < 64; m <<= 1) v += __shfl_xor(v, m);
  if ((t & 63) == 0) red[t >> 6] = v;
  __syncthreads();
  v = red[0] + red[1] + red[2] + red[3];
  __syncthreads();
  return v;
}
__device__ __forceinline__ float block_reduce_max(float v, volatile float* red) {
  int t = threadIdx.x;
#pragma unroll
  for (int m = 1; m < 64; m <<= 1) v = fmaxf(v, __shfl_xor(v, m));
  if ((t & 63) == 0) red[t >> 6] = v;
  __syncthreads();
  v = fmaxf(fmaxf(red[0], red[1]), fmaxf(red[2], red[3]));
  __syncthreads();
  return v;
}

// K1: one pass over x. Per 64c x 64hw tile: partial g (atomic), partial spatial
// dot (atomic), and bf16 transpose-out in MFMA-fragment-swizzled layout.
// Blocks with b==0 also convert res_w -> wbfS (same swizzle).
__global__ __launch_bounds__(256) void k1_stats_transpose(
    const float* __restrict__ x, const float* __restrict__ w_conv1,
    const float* __restrict__ res_w,
    float* __restrict__ g_sum, float* __restrict__ spat,
    unsigned short* __restrict__ xTS, unsigned short* __restrict__ wbfS) {
  __shared__ float sp_lds[16][64];
  __shared__ unsigned short t_lds[64 * 72];  // [hw][c], pad 72
  const int t = threadIdx.x;
  const int b = blockIdx.z;
  const int c0 = blockIdx.y * 64;
  const int h0 = blockIdx.x * 64;
  const int cg = t >> 4;
  const int hg = t & 15;

  float vv[4][4];
  float wc[4];
  const float* xb = x + ((size_t)(b * NC + c0 + cg * 4) * HW) + h0 + hg * 4;
#pragma unroll
  for (int i = 0; i < 4; i++) {
    float4 v = *(const float4*)(xb + (size_t)i * HW);
    vv[i][0] = v.x; vv[i][1] = v.y; vv[i][2] = v.z; vv[i][3] = v.w;
    wc[i] = w_conv1[c0 + cg * 4 + i];
  }
#pragma unroll
  for (int i = 0; i < 4; i++) {
    float s = vv[i][0] + vv[i][1] + vv[i][2] + vv[i][3];
    s += __shfl_xor(s, 1); s += __shfl_xor(s, 2);
    s += __shfl_xor(s, 4); s += __shfl_xor(s, 8);
    if (hg == 0) atomicAdd(&g_sum[b * NC + c0 + cg * 4 + i], s);
  }
  {
    float4 sp;
    sp.x = vv[0][0] * wc[0] + vv[1][0] * wc[1] + vv[2][0] * wc[2] + vv[3][0] * wc[3];
    sp.y = vv[0][1] * wc[0] + vv[1][1] * wc[1] + vv[2][1] * wc[2] + vv[3][1] * wc[3];
    sp.z = vv[0][2] * wc[0] + vv[1][2] * wc[1] + vv[2][2] * wc[2] + vv[3][2] * wc[3];
    sp.w = vv[0][3] * wc[0] + vv[1][3] * wc[1] + vv[2][3] * wc[2] + vv[3][3] * wc[3];
    *(float4*)&sp_lds[cg][hg * 4] = sp;
  }
#pragma unroll
  for (int j = 0; j < 4; j++) {
    ushort4 u;
    u.x = f2bf(vv[0][j]); u.y = f2bf(vv[1][j]);
    u.z = f2bf(vv[2][j]); u.w = f2bf(vv[3][j]);
    *(ushort4*)&t_lds[(hg * 4 + j) * 72 + cg * 4] = u;
  }
  __syncthreads();
  if (t < 64) {
    float s = 0.f;
#pragma unroll
    for (int i = 0; i < 16; i++) s += sp_lds[i][t];
    atomicAdd(&spat[b * HW + h0 + t], s);
  }
  const int w = t >> 6, l = t & 63;
#pragma unroll
  for (int ff = w; ff < 8; ff += 4) {
    const int fr = ff >> 1, fk = ff & 1;
    short8 v = *(const short8*)&t_lds[(fr * 16 + (l & 15)) * 72 + (fk * 4 + (l >> 4)) * 8];
    size_t tile = (size_t)(b * 256 + (h0 >> 4) + fr) * 16 + (c0 >> 5) + fk;
    *(short8*)(xTS + tile * 512 + l * 8) = v;
  }
  if (b == 0 && t < 64) {
    const int q = blockIdx.y * 64 + blockIdx.x;  // o row 0..511
    float4 a = *(const float4*)(res_w + (size_t)q * 512 + t * 8);
    float4 c2 = *(const float4*)(res_w + (size_t)q * 512 + t * 8 + 4);
    short8 v;
    v[0] = (short)f2bf(a.x); v[1] = (short)f2bf(a.y);
    v[2] = (short)f2bf(a.z); v[3] = (short)f2bf(a.w);
    v[4] = (short)f2bf(c2.x); v[5] = (short)f2bf(c2.y);
    v[6] = (short)f2bf(c2.z); v[7] = (short)f2bf(c2.w);
    const int lq = (q & 15) + ((t & 3) << 4);
    *(short8*)(wbfS + ((size_t)(q >> 4) * 16 + (t >> 2)) * 512 + lq * 8) = v;
  }
}

// K2 COOP (512 blocks x 256 threads, cooperative): the whole k2 chain in one
// dispatch with 6 grid.sync()s. Wave-per-dot GEMVs (proven in r6: 2048 waves,
// one row-dot per wave). Stage order / reduce structures are bitwise-identical
// to the round-6 split kernels.
//   S0: mv1 (2048 dots) + s=hsig(spat) pass + Ssum atomic (blocks 0..31)
//   S1: mv2 (4096 dots, 2/wave)
//   S2: LayerNorm -> t_arr (blocks 0..7)
//   S3: floorsum P (block = (b, 8-col group); per-col order unchanged)
//   S4: sk1 (2048 dots)
//   S5: sk2 (4096 dots, 2/wave)
//   S6: softmax + coef (blocks 0..7)
__global__ __launch_bounds__(256) void k2_coop(
    const float* __restrict__ g_sum, const float* __restrict__ spat,
    const float* __restrict__ w_b1, const float* __restrict__ b_b1,
    const float* __restrict__ w_b2, const float* __restrict__ b_b2,
    const float* __restrict__ ln_g, const float* __restrict__ ln_b,
    const float* __restrict__ sk_w1, const float* __restrict__ sk_w2,
    float* __restrict__ s_out, float* __restrict__ Ssum,
    float* __restrict__ ca1, float* __restrict__ ca2,
    float* __restrict__ t_arr, float* __restrict__ P,
    float* __restrict__ u1, float* __restrict__ u2,
    float* __restrict__ coef) {
  __shared__ float s_l[4096];
  __shared__ float red[4];
  cg::grid_group grid = cg::this_grid();
  const int t = threadIdx.x, blk = blockIdx.x;
  const int l = t & 63;
  const int Wv = blk * 4 + (t >> 6);  // 0..2047

  // ---- S0: mv1 + s-pass ----
  {
    const int b = Wv >> 8, o = Wv & 255;
    const float* wr = w_b1 + (size_t)o * 512 + l * 8;
    float4 wa = *(const float4*)wr;
    float4 wb = *(const float4*)(wr + 4);
    const float* gr = g_sum + b * NC + l * 8;
    float4 ga = *(const float4*)gr;
    float4 gb = *(const float4*)(gr + 4);
    float p = wa.x * ga.x + wa.y * ga.y + wa.z * ga.z + wa.w * ga.w +
              wb.x * gb.x + wb.y * gb.y + wb.z * gb.z + wb.w * gb.w;
    p = wave_reduce(p);
    if (l == 0) ca1[b * 256 + o] = fmaxf(p * (1.0f / 4096.0f) + b_b1[o], 0.0f);
  }
  if (blk < 32) {
    const int b2 = blk >> 2;
    const int i4 = (blk & 3) * 256 + t;
    float4 v = ((const float4*)(spat + (size_t)b2 * HW))[i4];
    float4 os;
    os.x = hsig(v.x); os.y = hsig(v.y); os.z = hsig(v.z); os.w = hsig(v.w);
    ((float4*)(s_out + (size_t)b2 * HW))[i4] = os;
    float sum = wave_reduce(os.x + os.y + os.z + os.w);
    if (l == 0) atomicAdd(&Ssum[b2], sum);
  }
  grid.sync();

  // ---- S1: mv2 (2 rows/wave) ----
  {
    const int b = Wv >> 8, ob = Wv & 255;
    float4 cv = ((const float4*)(ca1 + b * 256))[l];
#pragma unroll
    for (int h = 0; h < 2; h++) {
      const int o = ob + h * 256;
      float4 wv = ((const float4*)(w_b2 + (size_t)o * 256))[l];
      float p = wv.x * cv.x + wv.y * cv.y + wv.z * cv.z + wv.w * cv.w;
      p = wave_reduce(p);
      if (l == 0) ca2[b * NC + o] = hsig(p + b_b2[o]);
    }
  }
  grid.sync();

  // ---- S2: LayerNorm (blocks 0..7) ----
  if (blk < 8) {
    const int b = blk;
    float v0 = ca2[b * NC + t], v1 = ca2[b * NC + t + 256];
    float S = block_reduce_sum(v0 + v1, red);
    float SQ = block_reduce_sum(v0 * v0 + v1 * v1, red);
    float mu = S * (1.0f / 512.0f);
    float var = SQ * (1.0f / 512.0f) - mu * mu;
    float rstd = rsqrtf(var + 1e-6f);
    t_arr[b * NC + t] = (v0 - mu) * rstd * ln_g[t] + ln_b[t];
    t_arr[b * NC + t + 256] = (v1 - mu) * rstd * ln_g[t + 256] + ln_b[t + 256];
  }
  grid.sync();

  // ---- S3: floorsum (block = (b, cg2): 8 cols; per-col sum order as r6) ----
  {
    const int b = blk >> 6, cg2 = blk & 63;
    const float* sb = s_out + (size_t)b * HW;
#pragma unroll
    for (int i = 0; i < 16; i++) s_l[t + i * 256] = sb[t + i * 256];
    __syncthreads();
    const int w = t >> 6;
#pragma unroll
    for (int j = 0; j < 2; j++) {
      const int c = cg2 * 8 + w * 2 + j;
      const float tc = t_arr[b * NC + c];
      float sum = 0.f;
#pragma unroll 8
      for (int i = 0; i < 64; i++) sum += floorf((s_l[l + i * 64] + tc) * 0.5f);
      sum = wave_reduce(sum);
      if (l == 0) P[b * NC + c] = sum;
    }
  }
  grid.sync();

  // ---- S4: sk1 ----
  {
    const int b = Wv >> 8, o = Wv & 255;
    const float Ss = Ssum[b];
    const float* wr = sk_w1 + (size_t)o * 512 + l * 8;
    float4 wa = *(const float4*)wr;
    float4 wb = *(const float4*)(wr + 4);
    const float* tr = t_arr + b * NC + l * 8;
    const float* pr = P + b * NC + l * 8;
    float4 ta = *(const float4*)tr, tb = *(const float4*)(tr + 4);
    float4 Pa = *(const float4*)pr, Pb = *(const float4*)(pr + 4);
    float4 ua, ub;
    ua.x = ta.x * Ss + Pa.x; ua.y = ta.y * Ss + Pa.y;
    ua.z = ta.z * Ss + Pa.z; ua.w = ta.w * Ss + Pa.w;
    ub.x = tb.x * Ss + Pb.x; ub.y = tb.y * Ss + Pb.y;
    ub.z = tb.z * Ss + Pb.z; ub.w = tb.w * Ss + Pb.w;
    float p = wa.x * ua.x + wa.y * ua.y + wa.z * ua.z + wa.w * ua.w +
              wb.x * ub.x + wb.y * ub.y + wb.z * ub.z + wb.w * ub.w;
    p = wave_reduce(p) * (1.0f / 4096.0f);
    if (l == 0) u1[b * 256 + o] = fmaxf(p, 0.0f);
  }
  grid.sync();

  // ---- S5: sk2 (2 rows/wave) ----
  {
    const int b = Wv >> 8, ob = Wv & 255;
    float4 cv = ((const float4*)(u1 + b * 256))[l];
#pragma unroll
    for (int h = 0; h < 2; h++) {
      const int o = ob + h * 256;
      float4 wv = ((const float4*)(sk_w2 + (size_t)o * 256))[l];
      float p = wv.x * cv.x + wv.y * cv.y + wv.z * cv.z + wv.w * cv.w;
      p = wave_reduce(p);
      if (l == 0) u2[b * NC + o] = fmaxf(p, 0.0f);
    }
  }
  grid.sync();

  // ---- S6: softmax + coef (blocks 0..7) ----
  if (blk < 8) {
    const int b = blk;
    const float Ss = Ssum[b];
    float v0 = u2[b * NC + t], v1 = u2[b * NC + t + 256];
    float M = block_reduce_max(fmaxf(v0, v1), red);
    float e0 = __expf(v0 - M), e1 = __expf(v1 - M);
    float Z = block_reduce_sum(e0 + e1, red);
    float inv = 1.0f / Z;
#pragma unroll
    for (int h = 0; h < 2; h++) {
      const int o = t + h * 256;
      float a = (h == 0 ? e0 : e1) * inv;
      float tc = t_arr[b * NC + o];
      float Pv = P[b * NC + o];
      float c1 = a * tc;
      float c2 = 1.0f - a;
      float c3 = c1 * Ss + c2 * Pv;
      float4 cf = {c1, c2, c3, tc};
      *(float4*)(coef + (size_t)(b * NC + o) * 4) = cf;
    }
  }
}

// K3 v3 (proven 44 µs): bf16 MFMA, 2-phase global_load_lds pipeline.
// Block tile 128x128, K-step 32; grid (32,4,8) = 1024 blocks = 4/CU.
// 4 waves as 2(M) x 2(N), wave tile 64x64 -> acc[4][4].
__global__ __launch_bounds__(256, 4) void k3_gemm_epilogue(
    const unsigned short* __restrict__ wbfS, const unsigned short* __restrict__ xTS,
    const float* __restrict__ x, const float* __restrict__ s,
    const float* __restrict__ coef, float* __restrict__ out) {
  __shared__ __align__(16) char smem[32768];  // 2 x 16KB stage / 17KB epilogue
  const int t = threadIdx.x;
  const int bx = blockIdx.x, mz = blockIdx.y, b = blockIdx.z;
  const int w = t >> 6, l = t & 63;
  const int wm = w >> 1, wn = w & 1;
  const int l16 = l & 15, quad = l >> 4;

  f32x4 acc[4][4];
#pragma unroll
  for (int mi = 0; mi < 4; mi++)
#pragma unroll
    for (int ni = 0; ni < 4; ni++) {
      f32x4 z = {0.f, 0.f, 0.f, 0.f};
      acc[mi][ni] = z;
    }

  const char* gA0 = (const char*)wbfS + ((size_t)(mz * 8 + 2 * w) * 16) * 1024 + l * 16;
  const char* gA1 = gA0 + 16 * 1024;
  const char* gB0 = (const char*)xTS + ((size_t)(b * 256 + bx * 8 + 2 * w) * 16) * 1024 + l * 16;
  const char* gB1 = gB0 + 16 * 1024;
  char* lA0 = smem + (2 * w) * 1024;
  char* lA1 = smem + (2 * w + 1) * 1024;
  char* lB0 = smem + 8192 + (2 * w) * 1024;
  char* lB1 = smem + 8192 + (2 * w + 1) * 1024;
  const char* pA = smem + wm * 4096 + l * 16;
  const char* pB = smem + 8192 + wn * 4096 + l * 16;

#define K3_STAGE(buf, kk) do {                                  \
    gload16(gA0 + (kk) * 1024, lA0 + (buf) * 16384);            \
    gload16(gA1 + (kk) * 1024, lA1 + (buf) * 16384);            \
    gload16(gB0 + (kk) * 1024, lB0 + (buf) * 16384);            \
    gload16(gB1 + (kk) * 1024, lB1 + (buf) * 16384);            \
  } while (0)

#define K3_COMPUTE(buf) do {                                    \
    short8 af[4], bfr[4];                                       \
    _Pragma("unroll")                                           \
    for (int mi = 0; mi < 4; mi++)                              \
      af[mi] = *(const short8*)(pA + (buf) * 16384 + mi * 1024);\
    _Pragma("unroll")                                           \
    for (int ni = 0; ni < 4; ni++)                              \
      bfr[ni] = *(const short8*)(pB + (buf) * 16384 + ni * 1024);\
    _Pragma("unroll")                                           \
    for (int mi = 0; mi < 4; mi++)                              \
      _Pragma("unroll")                                         \
      for (int ni = 0; ni < 4; ni++)                            \
        acc[mi][ni] = __builtin_amdgcn_mfma_f32_16x16x32_bf16(  \
            af[mi], bfr[ni], acc[mi][ni], 0, 0, 0);             \
  } while (0)

  K3_STAGE(0, 0);
  __syncthreads();
#pragma unroll
  for (int kk = 0; kk < 16; kk += 2) {
    K3_STAGE(1, kk + 1);   // async loads in flight across the compute
    K3_COMPUTE(0);
    __syncthreads();       // drains vmcnt(0): buf1 ready
    if (kk + 2 < 16) K3_STAGE(0, kk + 2);
    K3_COMPUTE(1);
    __syncthreads();       // buf0 ready (and final: LDS free for epilogue)
  }

  // Epilogue: per-wave LDS transpose (wave-synchronous), 16-row chunks.
  float* eb = (float*)smem + w * 1088;  // 16 x 68 floats per wave
  const int row = l >> 2, cb = (l & 3) * 16;
  const int colb = bx * 128 + wn * 64 + cb;
  const float* sp = s + b * HW + colb;
  float4 sv[4];
#pragma unroll
  for (int j = 0; j < 4; j++) sv[j] = *(const float4*)(sp + 4 * j);
#pragma unroll
  for (int mi = 0; mi < 4; mi++) {
#pragma unroll
    for (int ni = 0; ni < 4; ni++)
#pragma unroll
      for (int r = 0; r < 4; r++)
        eb[(quad * 4 + r) * 68 + ni * 16 + l16] = acc[mi][ni][r];
    const int o = mz * 128 + wm * 64 + mi * 16 + row;
    float4 cf = *(const float4*)(coef + (size_t)(b * NC + o) * 4);
    const size_t rbase = (size_t)(b * NC + o) * HW + colb;
#pragma unroll
    for (int j = 0; j < 4; j++) {
      f32x4 y = *(f32x4*)&eb[row * 68 + cb + 4 * j];
      float4 svj = sv[j];
      float4 xv = *(const float4*)(x + rbase + 4 * j);
      float4 ov;
      ov.x = xv.x * (cf.x * svj.x + cf.y * floorf((svj.x + cf.w) * 0.5f)) + cf.z + y.x;
      ov.y = xv.y * (cf.x * svj.y + cf.y * floorf((svj.y + cf.w) * 0.5f)) + cf.z + y.y;
      ov.z = xv.z * (cf.x * svj.z + cf.y * floorf((svj.z + cf.w) * 0.5f)) + cf.z + y.z;
      ov.w = xv.w * (cf.x * svj.w + cf.y * floorf((svj.w + cf.w) * 0.5f)) + cf.z + y.w;
      *(float4*)(out + rbase + 4 * j) = ov;
    }
  }
#undef K3_STAGE
#undef K3_COMPUTE
}

extern "C" void kernel_launch(void* const* d_in, const int* in_sizes, int n_in,
                              void* d_out, int out_size, void* d_ws, size_t ws_size,
                              hipStream_t stream) {
  const float* x       = (const float*)d_in[0];
  const float* w_b1    = (const float*)d_in[1];
  const float* b_b1    = (const float*)d_in[2];
  const float* w_b2    = (const float*)d_in[3];
  const float* b_b2    = (const float*)d_in[4];
  const float* w_conv1 = (const float*)d_in[5];
  const float* ln_g    = (const float*)d_in[6];
  const float* ln_b    = (const float*)d_in[7];
  const float* sk_w1   = (const float*)d_in[8];
  const float* sk_w2   = (const float*)d_in[9];
  const float* res_w   = (const float*)d_in[10];
  float* out = (float*)d_out;
  char* ws = (char*)d_ws;

  float* g_sum = (float*)(ws + 0x00000);          // 16 KB  (atomic)
  float* spat  = (float*)(ws + 0x08000);          // 128 KB (atomic)
  float* Ssum  = (float*)(ws + 0x28000);          // 32 B   (atomic)
  float* t_arr = (float*)(ws + 0x29000);          // 16 KB
  float* P     = (float*)(ws + 0x30000);          // 16 KB
  float* coef  = (float*)(ws + 0x38000);          // 64 KB
  float* s     = (float*)(ws + 0x50000);          // 128 KB
  float* ca1   = (float*)(ws + 0x70000);          // 8 KB
  float* u1    = (float*)(ws + 0x72000);          // 8 KB
  float* ca2   = (float*)(ws + 0x74000);          // 16 KB
  float* u2    = (float*)(ws + 0x78000);          // 16 KB
  unsigned short* wbfS = (unsigned short*)(ws + 0x80000);   // 512 KB
  unsigned short* xTS  = (unsigned short*)(ws + 0x100000);  // 32 MB

  hipMemsetAsync(ws, 0, 0x28040, stream);  // zero g_sum, spat, Ssum
  k1_stats_transpose<<<dim3(64, 8, 8), 256, 0, stream>>>(x, w_conv1, res_w, g_sum, spat, xTS, wbfS);
  {
    void* args[] = {(void*)&g_sum, (void*)&spat, (void*)&w_b1, (void*)&b_b1,
                    (void*)&w_b2, (void*)&b_b2, (void*)&ln_g, (void*)&ln_b,
                    (void*)&sk_w1, (void*)&sk_w2, (void*)&s, (void*)&Ssum,
                    (void*)&ca1, (void*)&ca2, (void*)&t_arr, (void*)&P,
                    (void*)&u1, (void*)&u2, (void*)&coef};
    hipLaunchCooperativeKernel((void*)k2_coop, dim3(512), dim3(256), args, 0, stream);
  }
  k3_gemm_epilogue<<<dim3(32, 4, 8), 256, 0, stream>>>(wbfS, xTS, x, s, coef, out);
}

// Round 9
// 236.213 us; speedup vs baseline: 2.1524x; 2.1524x over previous
//
#include <hip/hip_runtime.h>
#include <stdint.h>

#define HW 4096
#define NC 512
#define NB 8

typedef __attribute__((ext_vector_type(8))) short short8;
typedef __attribute__((ext_vector_type(4))) float f32x4;

__device__ __forceinline__ unsigned short f2bf(float f) {
  unsigned int u = __builtin_bit_cast(unsigned int, f);
  unsigned int r = (u + 0x7FFFu + ((u >> 16) & 1u)) >> 16;
  return (unsigned short)r;
}
__device__ __forceinline__ float hsig(float v) {
  return fminf(fmaxf((v + 3.0f) * (1.0f / 6.0f), 0.0f), 1.0f);
}

__device__ __forceinline__ void gload16(const void* g, void* l) {
  __builtin_amdgcn_global_load_lds(
      (const __attribute__((address_space(1))) unsigned int*)g,
      (__attribute__((address_space(3))) unsigned int*)l, 16, 0, 0);
}

// Full-wave (64-lane) sum reduce.
__device__ __forceinline__ float wave_reduce(float p) {
#pragma unroll
  for (int m = 1; m < 64; m <<= 1) p += __shfl_xor(p, m);
  return p;
}

// 1024-thread (16-wave) block reductions.
__device__ __forceinline__ float block_reduce_sum16(float v, volatile float* red) {
  int t = threadIdx.x;
#pragma unroll
  for (int m = 1; m < 64; m <<= 1) v += __shfl_xor(v, m);
  if ((t & 63) == 0) red[t >> 6] = v;
  __syncthreads();
  v = 0.f;
#pragma unroll
  for (int i = 0; i < 16; i++) v += red[i];
  __syncthreads();
  return v;
}
__device__ __forceinline__ float block_reduce_max16(float v, volatile float* red) {
  int t = threadIdx.x;
#pragma unroll
  for (int m = 1; m < 64; m <<= 1) v = fmaxf(v, __shfl_xor(v, m));
  if ((t & 63) == 0) red[t >> 6] = v;
  __syncthreads();
  v = red[0];
#pragma unroll
  for (int i = 1; i < 16; i++) v = fmaxf(v, red[i]);
  __syncthreads();
  return v;
}

// K1: one pass over x. Per 64c x 64hw tile: partial g (atomic), partial spatial
// dot (atomic), and bf16 transpose-out in MFMA-fragment-swizzled layout.
// Blocks with b==0 also convert res_w -> wbfS (same swizzle).
__global__ __launch_bounds__(256) void k1_stats_transpose(
    const float* __restrict__ x, const float* __restrict__ w_conv1,
    const float* __restrict__ res_w,
    float* __restrict__ g_sum, float* __restrict__ spat,
    unsigned short* __restrict__ xTS, unsigned short* __restrict__ wbfS) {
  __shared__ float sp_lds[16][64];
  __shared__ unsigned short t_lds[64 * 72];  // [hw][c], pad 72
  const int t = threadIdx.x;
  const int b = blockIdx.z;
  const int c0 = blockIdx.y * 64;
  const int h0 = blockIdx.x * 64;
  const int cg = t >> 4;
  const int hg = t & 15;

  float vv[4][4];
  float wc[4];
  const float* xb = x + ((size_t)(b * NC + c0 + cg * 4) * HW) + h0 + hg * 4;
#pragma unroll
  for (int i = 0; i < 4; i++) {
    float4 v = *(const float4*)(xb + (size_t)i * HW);
    vv[i][0] = v.x; vv[i][1] = v.y; vv[i][2] = v.z; vv[i][3] = v.w;
    wc[i] = w_conv1[c0 + cg * 4 + i];
  }
#pragma unroll
  for (int i = 0; i < 4; i++) {
    float s = vv[i][0] + vv[i][1] + vv[i][2] + vv[i][3];
    s += __shfl_xor(s, 1); s += __shfl_xor(s, 2);
    s += __shfl_xor(s, 4); s += __shfl_xor(s, 8);
    if (hg == 0) atomicAdd(&g_sum[b * NC + c0 + cg * 4 + i], s);
  }
  {
    float4 sp;
    sp.x = vv[0][0] * wc[0] + vv[1][0] * wc[1] + vv[2][0] * wc[2] + vv[3][0] * wc[3];
    sp.y = vv[0][1] * wc[0] + vv[1][1] * wc[1] + vv[2][1] * wc[2] + vv[3][1] * wc[3];
    sp.z = vv[0][2] * wc[0] + vv[1][2] * wc[1] + vv[2][2] * wc[2] + vv[3][2] * wc[3];
    sp.w = vv[0][3] * wc[0] + vv[1][3] * wc[1] + vv[2][3] * wc[2] + vv[3][3] * wc[3];
    *(float4*)&sp_lds[cg][hg * 4] = sp;
  }
#pragma unroll
  for (int j = 0; j < 4; j++) {
    ushort4 u;
    u.x = f2bf(vv[0][j]); u.y = f2bf(vv[1][j]);
    u.z = f2bf(vv[2][j]); u.w = f2bf(vv[3][j]);
    *(ushort4*)&t_lds[(hg * 4 + j) * 72 + cg * 4] = u;
  }
  __syncthreads();
  if (t < 64) {
    float s = 0.f;
#pragma unroll
    for (int i = 0; i < 16; i++) s += sp_lds[i][t];
    atomicAdd(&spat[b * HW + h0 + t], s);
  }
  const int w = t >> 6, l = t & 63;
#pragma unroll
  for (int ff = w; ff < 8; ff += 4) {
    const int fr = ff >> 1, fk = ff & 1;
    short8 v = *(const short8*)&t_lds[(fr * 16 + (l & 15)) * 72 + (fk * 4 + (l >> 4)) * 8];
    size_t tile = (size_t)(b * 256 + (h0 >> 4) + fr) * 16 + (c0 >> 5) + fk;
    *(short8*)(xTS + tile * 512 + l * 8) = v;
  }
  if (b == 0 && t < 64) {
    const int q = blockIdx.y * 64 + blockIdx.x;  // o row 0..511
    float4 a = *(const float4*)(res_w + (size_t)q * 512 + t * 8);
    float4 c2 = *(const float4*)(res_w + (size_t)q * 512 + t * 8 + 4);
    short8 v;
    v[0] = (short)f2bf(a.x); v[1] = (short)f2bf(a.y);
    v[2] = (short)f2bf(a.z); v[3] = (short)f2bf(a.w);
    v[4] = (short)f2bf(c2.x); v[5] = (short)f2bf(c2.y);
    v[6] = (short)f2bf(c2.z); v[7] = (short)f2bf(c2.w);
    const int lq = (q & 15) + ((t & 3) << 4);
    *(short8*)(wbfS + ((size_t)(q >> 4) * 16 + (t >> 2)) * 512 + lq * 8) = v;
  }
}

// K2 FRONT (8 blocks x 1024 threads, one per batch): s=hsig(spat)+Ssum;
// mv1; mv2; LayerNorm -> t_arr. Wave-per-row GEMV with EXPLICIT 4-row ILP
// (4 independent dots' loads in flight before the 4 reduces) — fixes r5's
// 24-VGPR serialization; coalesced rows fix r4's 64-line overfetch.
// Per-dot lane math bitwise-identical to the round-6 split kernels.
// Block-internal __syncthreads between stages (grid.sync costs ~53 us! r7).
__global__ __launch_bounds__(1024) void k2_front(
    const float* __restrict__ g_sum, const float* __restrict__ spat,
    const float* __restrict__ w_b1, const float* __restrict__ b_b1,
    const float* __restrict__ w_b2, const float* __restrict__ b_b2,
    const float* __restrict__ ln_g, const float* __restrict__ ln_b,
    float* __restrict__ s_out, float* __restrict__ Ssum,
    float* __restrict__ t_arr) {
  __shared__ float ca1_l[256];
  __shared__ float ca2_l[512];
  __shared__ float red[16];
  const int b = blockIdx.x, t = threadIdx.x;
  const int w = t >> 6, l = t & 63;

  // S0: s = hsig(spat), Ssum (block reduce, deterministic)
  {
    float4 v = ((const float4*)(spat + (size_t)b * HW))[t];
    float4 os;
    os.x = hsig(v.x); os.y = hsig(v.y); os.z = hsig(v.z); os.w = hsig(v.w);
    ((float4*)(s_out + (size_t)b * HW))[t] = os;
    float Ss = block_reduce_sum16(os.x + os.y + os.z + os.w, red);
    if (t == 0) Ssum[b] = Ss;
  }

  // S1: mv1 — 256 rows of 512. Wave w rows o = w + 16*(4jj+q), 4-deep ILP.
  float ga[8];
  {
    const float4 g0 = *(const float4*)(g_sum + b * NC + l * 8);
    const float4 g1 = *(const float4*)(g_sum + b * NC + l * 8 + 4);
    ga[0] = g0.x; ga[1] = g0.y; ga[2] = g0.z; ga[3] = g0.w;
    ga[4] = g1.x; ga[5] = g1.y; ga[6] = g1.z; ga[7] = g1.w;
  }
#pragma unroll
  for (int jj = 0; jj < 4; jj++) {
    float pr[4];
#pragma unroll
    for (int q = 0; q < 4; q++) {
      const int o = w + 16 * (jj * 4 + q);
      const float* wr = w_b1 + (size_t)o * 512 + l * 8;
      float4 wa = *(const float4*)wr;
      float4 wb = *(const float4*)(wr + 4);
      pr[q] = wa.x * ga[0] + wa.y * ga[1] + wa.z * ga[2] + wa.w * ga[3] +
              wb.x * ga[4] + wb.y * ga[5] + wb.z * ga[6] + wb.w * ga[7];
    }
#pragma unroll
    for (int q = 0; q < 4; q++) pr[q] = wave_reduce(pr[q]);
    if (l == 0) {
#pragma unroll
      for (int q = 0; q < 4; q++) {
        const int o = w + 16 * (jj * 4 + q);
        ca1_l[o] = fmaxf(pr[q] * (1.0f / 4096.0f) + b_b1[o], 0.0f);
      }
    }
  }
  __syncthreads();

  // S2: mv2 — 512 rows of 256.
  {
    float4 c4 = *(float4*)&ca1_l[l * 4];
#pragma unroll
    for (int jj = 0; jj < 8; jj++) {
      float pr[4];
#pragma unroll
      for (int q = 0; q < 4; q++) {
        const int o = w + 16 * (jj * 4 + q);
        float4 wv = ((const float4*)(w_b2 + (size_t)o * 256))[l];
        pr[q] = wv.x * c4.x + wv.y * c4.y + wv.z * c4.z + wv.w * c4.w;
      }
#pragma unroll
      for (int q = 0; q < 4; q++) pr[q] = wave_reduce(pr[q]);
      if (l == 0) {
#pragma unroll
        for (int q = 0; q < 4; q++) {
          const int o = w + 16 * (jj * 4 + q);
          ca2_l[o] = hsig(pr[q] + b_b2[o]);
        }
      }
    }
  }
  __syncthreads();

  // S3: LayerNorm over ca2 (512 values; threads >=512 contribute 0)
  {
    float val = (t < 512) ? ca2_l[t] : 0.f;
    float S = block_reduce_sum16(val, red);
    float SQ = block_reduce_sum16(val * val, red);
    float mu = S * (1.0f / 512.0f);
    float var = SQ * (1.0f / 512.0f) - mu * mu;
    float rstd = rsqrtf(var + 1e-6f);
    if (t < 512) t_arr[b * NC + t] = (val - mu) * rstd * ln_g[t] + ln_b[t];
  }
}

// K2bF: P[b][c] = sum_hw floor((s + t)/2). s[b][:] staged once in LDS.
// Stays a separate 256-block kernel: 16M floor-terms need ~256 CUs
// (8-block fusion would be ~20 us of VALU on 8 CUs).
__global__ __launch_bounds__(256) void k2b_floorsum(
    const float* __restrict__ s, const float* __restrict__ t_arr, float* __restrict__ P) {
  __shared__ float s_l[4096];
  const int t = threadIdx.x;
  const int b = blockIdx.y;
  const int c0 = blockIdx.x * 16;
  const float* sb = s + b * HW;
#pragma unroll
  for (int i = 0; i < 16; i++) s_l[t + i * 256] = sb[t + i * 256];
  __syncthreads();
  const int w = t >> 6, l = t & 63;
#pragma unroll
  for (int j = 0; j < 4; j++) {
    int c = c0 + w * 4 + j;
    float tc = t_arr[b * NC + c];
    float sum = 0.f;
#pragma unroll 8
    for (int i = 0; i < 64; i++) sum += floorf((s_l[l + i * 64] + tc) * 0.5f);
#pragma unroll
    for (int m = 1; m < 64; m <<= 1) sum += __shfl_xor(sum, m);
    if (l == 0) P[b * NC + c] = sum;
  }
}

// K2 BACK (8 blocks x 1024 threads): sk1; sk2; softmax -> coef.
// Same wave-per-row 4-deep-ILP GEMV structure as k2_front.
__global__ __launch_bounds__(1024) void k2_back(
    const float* __restrict__ t_arr, const float* __restrict__ P,
    const float* __restrict__ Ssum, const float* __restrict__ sk_w1,
    const float* __restrict__ sk_w2, float* __restrict__ coef) {
  __shared__ float u1_l[256];
  __shared__ float u2_l[512];
  __shared__ float red[16];
  const int b = blockIdx.x, t = threadIdx.x;
  const int w = t >> 6, l = t & 63;
  const float Ss = Ssum[b];

  // S0: sk1 — u computed inline per lane: u[c] = t*Ss + P (scale after reduce)
  float ua[8];
  {
    const float* tr = t_arr + b * NC + l * 8;
    const float* pr = P + b * NC + l * 8;
    float4 ta = *(const float4*)tr, tb = *(const float4*)(tr + 4);
    float4 Pa = *(const float4*)pr, Pb = *(const float4*)(pr + 4);
    ua[0] = ta.x * Ss + Pa.x; ua[1] = ta.y * Ss + Pa.y;
    ua[2] = ta.z * Ss + Pa.z; ua[3] = ta.w * Ss + Pa.w;
    ua[4] = tb.x * Ss + Pb.x; ua[5] = tb.y * Ss + Pb.y;
    ua[6] = tb.z * Ss + Pb.z; ua[7] = tb.w * Ss + Pb.w;
  }
#pragma unroll
  for (int jj = 0; jj < 4; jj++) {
    float pr[4];
#pragma unroll
    for (int q = 0; q < 4; q++) {
      const int o = w + 16 * (jj * 4 + q);
      const float* wr = sk_w1 + (size_t)o * 512 + l * 8;
      float4 wa = *(const float4*)wr;
      float4 wb = *(const float4*)(wr + 4);
      pr[q] = wa.x * ua[0] + wa.y * ua[1] + wa.z * ua[2] + wa.w * ua[3] +
              wb.x * ua[4] + wb.y * ua[5] + wb.z * ua[6] + wb.w * ua[7];
    }
#pragma unroll
    for (int q = 0; q < 4; q++) pr[q] = wave_reduce(pr[q]) * (1.0f / 4096.0f);
    if (l == 0) {
#pragma unroll
      for (int q = 0; q < 4; q++) {
        const int o = w + 16 * (jj * 4 + q);
        u1_l[o] = fmaxf(pr[q], 0.0f);
      }
    }
  }
  __syncthreads();

  // S1: sk2 — 512 rows of 256.
  {
    float4 c4 = *(float4*)&u1_l[l * 4];
#pragma unroll
    for (int jj = 0; jj < 8; jj++) {
      float pr[4];
#pragma unroll
      for (int q = 0; q < 4; q++) {
        const int o = w + 16 * (jj * 4 + q);
        float4 wv = ((const float4*)(sk_w2 + (size_t)o * 256))[l];
        pr[q] = wv.x * c4.x + wv.y * c4.y + wv.z * c4.z + wv.w * c4.w;
      }
#pragma unroll
      for (int q = 0; q < 4; q++) pr[q] = wave_reduce(pr[q]);
      if (l == 0) {
#pragma unroll
        for (int q = 0; q < 4; q++) {
          const int o = w + 16 * (jj * 4 + q);
          u2_l[o] = fmaxf(pr[q], 0.0f);
        }
      }
    }
  }
  __syncthreads();

  // S2: softmax over u2 (512) + coef
  {
    float val = (t < 512) ? u2_l[t] : -3.402823466e38f;
    float M = block_reduce_max16(val, red);
    float e = (t < 512) ? __expf(val - M) : 0.f;
    float Z = block_reduce_sum16(e, red);
    if (t < 512) {
      float a = e / Z;
      float tc = t_arr[b * NC + t];
      float Pv = P[b * NC + t];
      float c1 = a * tc;
      float c2 = 1.0f - a;
      float c3 = c1 * Ss + c2 * Pv;
      float4 cf = {c1, c2, c3, tc};
      *(float4*)(coef + (size_t)(b * NC + t) * 4) = cf;
    }
  }
}

// K3 v3 (proven 44 µs): bf16 MFMA, 2-phase global_load_lds pipeline.
// Block tile 128x128, K-step 32; grid (32,4,8) = 1024 blocks = 4/CU.
// 4 waves as 2(M) x 2(N), wave tile 64x64 -> acc[4][4].
__global__ __launch_bounds__(256, 4) void k3_gemm_epilogue(
    const unsigned short* __restrict__ wbfS, const unsigned short* __restrict__ xTS,
    const float* __restrict__ x, const float* __restrict__ s,
    const float* __restrict__ coef, float* __restrict__ out) {
  __shared__ __align__(16) char smem[32768];  // 2 x 16KB stage / 17KB epilogue
  const int t = threadIdx.x;
  const int bx = blockIdx.x, mz = blockIdx.y, b = blockIdx.z;
  const int w = t >> 6, l = t & 63;
  const int wm = w >> 1, wn = w & 1;
  const int l16 = l & 15, quad = l >> 4;

  f32x4 acc[4][4];
#pragma unroll
  for (int mi = 0; mi < 4; mi++)
#pragma unroll
    for (int ni = 0; ni < 4; ni++) {
      f32x4 z = {0.f, 0.f, 0.f, 0.f};
      acc[mi][ni] = z;
    }

  const char* gA0 = (const char*)wbfS + ((size_t)(mz * 8 + 2 * w) * 16) * 1024 + l * 16;
  const char* gA1 = gA0 + 16 * 1024;
  const char* gB0 = (const char*)xTS + ((size_t)(b * 256 + bx * 8 + 2 * w) * 16) * 1024 + l * 16;
  const char* gB1 = gB0 + 16 * 1024;
  char* lA0 = smem + (2 * w) * 1024;
  char* lA1 = smem + (2 * w + 1) * 1024;
  char* lB0 = smem + 8192 + (2 * w) * 1024;
  char* lB1 = smem + 8192 + (2 * w + 1) * 1024;
  const char* pA = smem + wm * 4096 + l * 16;
  const char* pB = smem + 8192 + wn * 4096 + l * 16;

#define K3_STAGE(buf, kk) do {                                  \
    gload16(gA0 + (kk) * 1024, lA0 + (buf) * 16384);            \
    gload16(gA1 + (kk) * 1024, lA1 + (buf) * 16384);            \
    gload16(gB0 + (kk) * 1024, lB0 + (buf) * 16384);            \
    gload16(gB1 + (kk) * 1024, lB1 + (buf) * 16384);            \
  } while (0)

#define K3_COMPUTE(buf) do {                                    \
    short8 af[4], bfr[4];                                       \
    _Pragma("unroll")                                           \
    for (int mi = 0; mi < 4; mi++)                              \
      af[mi] = *(const short8*)(pA + (buf) * 16384 + mi * 1024);\
    _Pragma("unroll")                                           \
    for (int ni = 0; ni < 4; ni++)                              \
      bfr[ni] = *(const short8*)(pB + (buf) * 16384 + ni * 1024);\
    _Pragma("unroll")                                           \
    for (int mi = 0; mi < 4; mi++)                              \
      _Pragma("unroll")                                         \
      for (int ni = 0; ni < 4; ni++)                            \
        acc[mi][ni] = __builtin_amdgcn_mfma_f32_16x16x32_bf16(  \
            af[mi], bfr[ni], acc[mi][ni], 0, 0, 0);             \
  } while (0)

  K3_STAGE(0, 0);
  __syncthreads();
#pragma unroll
  for (int kk = 0; kk < 16; kk += 2) {
    K3_STAGE(1, kk + 1);   // async loads in flight across the compute
    K3_COMPUTE(0);
    __syncthreads();       // drains vmcnt(0): buf1 ready
    if (kk + 2 < 16) K3_STAGE(0, kk + 2);
    K3_COMPUTE(1);
    __syncthreads();       // buf0 ready (and final: LDS free for epilogue)
  }

  // Epilogue: per-wave LDS transpose (wave-synchronous), 16-row chunks.
  float* eb = (float*)smem + w * 1088;  // 16 x 68 floats per wave
  const int row = l >> 2, cb = (l & 3) * 16;
  const int colb = bx * 128 + wn * 64 + cb;
  const float* sp = s + b * HW + colb;
  float4 sv[4];
#pragma unroll
  for (int j = 0; j < 4; j++) sv[j] = *(const float4*)(sp + 4 * j);
#pragma unroll
  for (int mi = 0; mi < 4; mi++) {
#pragma unroll
    for (int ni = 0; ni < 4; ni++)
#pragma unroll
      for (int r = 0; r < 4; r++)
        eb[(quad * 4 + r) * 68 + ni * 16 + l16] = acc[mi][ni][r];
    const int o = mz * 128 + wm * 64 + mi * 16 + row;
    float4 cf = *(const float4*)(coef + (size_t)(b * NC + o) * 4);
    const size_t rbase = (size_t)(b * NC + o) * HW + colb;
#pragma unroll
    for (int j = 0; j < 4; j++) {
      f32x4 y = *(f32x4*)&eb[row * 68 + cb + 4 * j];
      float4 svj = sv[j];
      float4 xv = *(const float4*)(x + rbase + 4 * j);
      float4 ov;
      ov.x = xv.x * (cf.x * svj.x + cf.y * floorf((svj.x + cf.w) * 0.5f)) + cf.z + y.x;
      ov.y = xv.y * (cf.x * svj.y + cf.y * floorf((svj.y + cf.w) * 0.5f)) + cf.z + y.y;
      ov.z = xv.z * (cf.x * svj.z + cf.y * floorf((svj.z + cf.w) * 0.5f)) + cf.z + y.z;
      ov.w = xv.w * (cf.x * svj.w + cf.y * floorf((svj.w + cf.w) * 0.5f)) + cf.z + y.w;
      *(float4*)(out + rbase + 4 * j) = ov;
    }
  }
#undef K3_STAGE
#undef K3_COMPUTE
}

extern "C" void kernel_launch(void* const* d_in, const int* in_sizes, int n_in,
                              void* d_out, int out_size, void* d_ws, size_t ws_size,
                              hipStream_t stream) {
  const float* x       = (const float*)d_in[0];
  const float* w_b1    = (const float*)d_in[1];
  const float* b_b1    = (const float*)d_in[2];
  const float* w_b2    = (const float*)d_in[3];
  const float* b_b2    = (const float*)d_in[4];
  const float* w_conv1 = (const float*)d_in[5];
  const float* ln_g    = (const float*)d_in[6];
  const float* ln_b    = (const float*)d_in[7];
  const float* sk_w1   = (const float*)d_in[8];
  const float* sk_w2   = (const float*)d_in[9];
  const float* res_w   = (const float*)d_in[10];
  float* out = (float*)d_out;
  char* ws = (char*)d_ws;

  float* g_sum = (float*)(ws + 0x00000);          // 16 KB  (atomic)
  float* spat  = (float*)(ws + 0x08000);          // 128 KB (atomic)
  float* Ssum  = (float*)(ws + 0x28000);          // 32 B
  float* t_arr = (float*)(ws + 0x29000);          // 16 KB
  float* P     = (float*)(ws + 0x30000);          // 16 KB
  float* coef  = (float*)(ws + 0x38000);          // 64 KB
  float* s     = (float*)(ws + 0x50000);          // 128 KB
  unsigned short* wbfS = (unsigned short*)(ws + 0x80000);   // 512 KB
  unsigned short* xTS  = (unsigned short*)(ws + 0x100000);  // 32 MB

  hipMemsetAsync(ws, 0, 0x28000, stream);  // zero g_sum, spat
  k1_stats_transpose<<<dim3(64, 8, 8), 256, 0, stream>>>(x, w_conv1, res_w, g_sum, spat, xTS, wbfS);
  k2_front<<<8, 1024, 0, stream>>>(g_sum, spat, w_b1, b_b1, w_b2, b_b2, ln_g, ln_b, s, Ssum, t_arr);
  k2b_floorsum<<<dim3(32, 8), 256, 0, stream>>>(s, t_arr, P);
  k2_back<<<8, 1024, 0, stream>>>(t_arr, P, Ssum, sk_w1, sk_w2, coef);
  k3_gemm_epilogue<<<dim3(32, 4, 8), 256, 0, stream>>>(wbfS, xTS, x, s, coef, out);
}

// Round 10
// 193.967 us; speedup vs baseline: 2.6212x; 1.2178x over previous
//
#include <hip/hip_runtime.h>
#include <stdint.h>

#define HW 4096
#define NC 512
#define NB 8

typedef __attribute__((ext_vector_type(8))) short short8;
typedef __attribute__((ext_vector_type(4))) float f32x4;

__device__ __forceinline__ unsigned short f2bf(float f) {
  unsigned int u = __builtin_bit_cast(unsigned int, f);
  unsigned int r = (u + 0x7FFFu + ((u >> 16) & 1u)) >> 16;
  return (unsigned short)r;
}
__device__ __forceinline__ float hsig(float v) {
  return fminf(fmaxf((v + 3.0f) * (1.0f / 6.0f), 0.0f), 1.0f);
}

__device__ __forceinline__ void gload16(const void* g, void* l) {
  __builtin_amdgcn_global_load_lds(
      (const __attribute__((address_space(1))) unsigned int*)g,
      (__attribute__((address_space(3))) unsigned int*)l, 16, 0, 0);
}

// Full-wave (64-lane) sum reduce.
__device__ __forceinline__ float wave_reduce(float p) {
#pragma unroll
  for (int m = 1; m < 64; m <<= 1) p += __shfl_xor(p, m);
  return p;
}

// 256-thread (4-wave) block reductions.
__device__ __forceinline__ float block_reduce_sum(float v, volatile float* red) {
  int t = threadIdx.x;
#pragma unroll
  for (int m = 1; m < 64; m <<= 1) v += __shfl_xor(v, m);
  if ((t & 63) == 0) red[t >> 6] = v;
  __syncthreads();
  v = red[0] + red[1] + red[2] + red[3];
  __syncthreads();
  return v;
}
__device__ __forceinline__ float block_reduce_max(float v, volatile float* red) {
  int t = threadIdx.x;
#pragma unroll
  for (int m = 1; m < 64; m <<= 1) v = fmaxf(v, __shfl_xor(v, m));
  if ((t & 63) == 0) red[t >> 6] = v;
  __syncthreads();
  v = fmaxf(fmaxf(red[0], red[1]), fmaxf(red[2], red[3]));
  __syncthreads();
  return v;
}

// K1: one pass over x. Per 64c x 64hw tile: partial g (atomic), partial spatial
// dot (atomic), and bf16 transpose-out in MFMA-fragment-swizzled layout.
// Blocks with b==0 also convert res_w -> wbfS (same swizzle).
__global__ __launch_bounds__(256) void k1_stats_transpose(
    const float* __restrict__ x, const float* __restrict__ w_conv1,
    const float* __restrict__ res_w,
    float* __restrict__ g_sum, float* __restrict__ spat,
    unsigned short* __restrict__ xTS, unsigned short* __restrict__ wbfS) {
  __shared__ float sp_lds[16][64];
  __shared__ unsigned short t_lds[64 * 72];  // [hw][c], pad 72
  const int t = threadIdx.x;
  const int b = blockIdx.z;
  const int c0 = blockIdx.y * 64;
  const int h0 = blockIdx.x * 64;
  const int cg = t >> 4;
  const int hg = t & 15;

  float vv[4][4];
  float wc[4];
  const float* xb = x + ((size_t)(b * NC + c0 + cg * 4) * HW) + h0 + hg * 4;
#pragma unroll
  for (int i = 0; i < 4; i++) {
    float4 v = *(const float4*)(xb + (size_t)i * HW);
    vv[i][0] = v.x; vv[i][1] = v.y; vv[i][2] = v.z; vv[i][3] = v.w;
    wc[i] = w_conv1[c0 + cg * 4 + i];
  }
#pragma unroll
  for (int i = 0; i < 4; i++) {
    float s = vv[i][0] + vv[i][1] + vv[i][2] + vv[i][3];
    s += __shfl_xor(s, 1); s += __shfl_xor(s, 2);
    s += __shfl_xor(s, 4); s += __shfl_xor(s, 8);
    if (hg == 0) atomicAdd(&g_sum[b * NC + c0 + cg * 4 + i], s);
  }
  {
    float4 sp;
    sp.x = vv[0][0] * wc[0] + vv[1][0] * wc[1] + vv[2][0] * wc[2] + vv[3][0] * wc[3];
    sp.y = vv[0][1] * wc[0] + vv[1][1] * wc[1] + vv[2][1] * wc[2] + vv[3][1] * wc[3];
    sp.z = vv[0][2] * wc[0] + vv[1][2] * wc[1] + vv[2][2] * wc[2] + vv[3][2] * wc[3];
    sp.w = vv[0][3] * wc[0] + vv[1][3] * wc[1] + vv[2][3] * wc[2] + vv[3][3] * wc[3];
    *(float4*)&sp_lds[cg][hg * 4] = sp;
  }
#pragma unroll
  for (int j = 0; j < 4; j++) {
    ushort4 u;
    u.x = f2bf(vv[0][j]); u.y = f2bf(vv[1][j]);
    u.z = f2bf(vv[2][j]); u.w = f2bf(vv[3][j]);
    *(ushort4*)&t_lds[(hg * 4 + j) * 72 + cg * 4] = u;
  }
  __syncthreads();
  if (t < 64) {
    float s = 0.f;
#pragma unroll
    for (int i = 0; i < 16; i++) s += sp_lds[i][t];
    atomicAdd(&spat[b * HW + h0 + t], s);
  }
  const int w = t >> 6, l = t & 63;
#pragma unroll
  for (int ff = w; ff < 8; ff += 4) {
    const int fr = ff >> 1, fk = ff & 1;
    short8 v = *(const short8*)&t_lds[(fr * 16 + (l & 15)) * 72 + (fk * 4 + (l >> 4)) * 8];
    size_t tile = (size_t)(b * 256 + (h0 >> 4) + fr) * 16 + (c0 >> 5) + fk;
    *(short8*)(xTS + tile * 512 + l * 8) = v;
  }
  if (b == 0 && t < 64) {
    const int q = blockIdx.y * 64 + blockIdx.x;  // o row 0..511
    float4 a = *(const float4*)(res_w + (size_t)q * 512 + t * 8);
    float4 c2 = *(const float4*)(res_w + (size_t)q * 512 + t * 8 + 4);
    short8 v;
    v[0] = (short)f2bf(a.x); v[1] = (short)f2bf(a.y);
    v[2] = (short)f2bf(a.z); v[3] = (short)f2bf(a.w);
    v[4] = (short)f2bf(c2.x); v[5] = (short)f2bf(c2.y);
    v[6] = (short)f2bf(c2.z); v[7] = (short)f2bf(c2.w);
    const int lq = (q & 15) + ((t & 3) << 4);
    *(short8*)(wbfS + ((size_t)(q >> 4) * 16 + (t >> 2)) * 512 + lq * 8) = v;
  }
}

// ---- k2 chain: r6's proven wave-per-dot kernels (512-1024 blocks, one
// row-dot per wave), with LN fused into floorsum and softmax fused into k3
// (redundant per-block recompute — no extra dispatch, no grid sync).

// K2 mv1 (512 blocks): wave W -> (b = W>>8, o = W&255):
// ca1[b][o] = relu(dot(w_b1[o], g_sum[b]) / 4096 + b_b1[o]).
// Blocks < 32 also do the s = hsig(spat) pass + Ssum atomic.
__global__ __launch_bounds__(256) void k2_mv1(
    const float* __restrict__ g_sum, const float* __restrict__ spat,
    const float* __restrict__ w_b1, const float* __restrict__ b_b1,
    float* __restrict__ s_out, float* __restrict__ Ssum,
    float* __restrict__ ca1) {
  const int l = threadIdx.x & 63;
  const int W = blockIdx.x * 4 + (threadIdx.x >> 6);
  const int b = W >> 8, o = W & 255;
  const float* wr = w_b1 + (size_t)o * 512 + l * 8;
  float4 wa = *(const float4*)wr;
  float4 wb = *(const float4*)(wr + 4);
  const float* gr = g_sum + b * NC + l * 8;
  float4 ga = *(const float4*)gr;
  float4 gb = *(const float4*)(gr + 4);
  float p = wa.x * ga.x + wa.y * ga.y + wa.z * ga.z + wa.w * ga.w +
            wb.x * gb.x + wb.y * gb.y + wb.z * gb.z + wb.w * gb.w;
  p = wave_reduce(p);
  if (l == 0) ca1[b * 256 + o] = fmaxf(p * (1.0f / 4096.0f) + b_b1[o], 0.0f);
  if (blockIdx.x < 32) {
    const int b2 = blockIdx.x >> 2;
    const int i4 = (blockIdx.x & 3) * 256 + threadIdx.x;
    float4 v = ((const float4*)(spat + (size_t)b2 * HW))[i4];
    float4 os;
    os.x = hsig(v.x); os.y = hsig(v.y); os.z = hsig(v.z); os.w = hsig(v.w);
    ((float4*)(s_out + (size_t)b2 * HW))[i4] = os;
    float sum = wave_reduce(os.x + os.y + os.z + os.w);
    if (l == 0) atomicAdd(&Ssum[b2], sum);
  }
}

// K2 mv2 (1024 blocks): wave W -> (b = W>>9, o = W&511):
// ca2[b][o] = hsig(dot(w_b2[o], ca1[b]) + b_b2[o]).
__global__ __launch_bounds__(256) void k2_mv2(
    const float* __restrict__ ca1, const float* __restrict__ w_b2,
    const float* __restrict__ b_b2, float* __restrict__ ca2) {
  const int l = threadIdx.x & 63;
  const int W = blockIdx.x * 4 + (threadIdx.x >> 6);
  const int b = W >> 9, o = W & 511;
  float4 wv = ((const float4*)(w_b2 + (size_t)o * 256))[l];
  float4 cv = ((const float4*)(ca1 + b * 256))[l];
  float p = wv.x * cv.x + wv.y * cv.y + wv.z * cv.z + wv.w * cv.w;
  p = wave_reduce(p);
  if (l == 0) ca2[b * NC + o] = hsig(p + b_b2[o]);
}

// K2bF+LN (256 blocks = (32 col-groups, 8 batches)): fuses k2_ln into the
// floorsum. Each block recomputes the LN stats from ca2 (2KB read, two
// 256-thread block reduces — bitwise identical to r6's k2_ln) and writes its
// own 16 t_arr columns (disjoint partition), then P[b][c] = sum_hw
// floor((s + t)/2) with s[b][:] staged in LDS.
__global__ __launch_bounds__(256) void k2b_floorsum_ln(
    const float* __restrict__ s, const float* __restrict__ ca2,
    const float* __restrict__ ln_g, const float* __restrict__ ln_b,
    float* __restrict__ t_arr, float* __restrict__ P) {
  __shared__ float s_l[4096];
  __shared__ float red[4];
  const int t = threadIdx.x;
  const int b = blockIdx.y;
  const int c0 = blockIdx.x * 16;
  // issue s staging first (visibility covered by the LN reduces' syncs)
  const float* sb = s + b * HW;
#pragma unroll
  for (int i = 0; i < 16; i++) s_l[t + i * 256] = sb[t + i * 256];
  // LN stats (identical math to r6 k2_ln)
  float v0 = ca2[b * NC + t], v1 = ca2[b * NC + t + 256];
  float S = block_reduce_sum(v0 + v1, red);
  float SQ = block_reduce_sum(v0 * v0 + v1 * v1, red);
  float mu = S * (1.0f / 512.0f);
  float var = SQ * (1.0f / 512.0f) - mu * mu;
  float rstd = rsqrtf(var + 1e-6f);
  const int w = t >> 6, l = t & 63;
#pragma unroll
  for (int j = 0; j < 4; j++) {
    int c = c0 + w * 4 + j;
    float tc = (ca2[b * NC + c] - mu) * rstd * ln_g[c] + ln_b[c];
    if (l == 0) t_arr[b * NC + c] = tc;
    float sum = 0.f;
#pragma unroll 8
    for (int i = 0; i < 64; i++) sum += floorf((s_l[l + i * 64] + tc) * 0.5f);
#pragma unroll
    for (int m = 1; m < 64; m <<= 1) sum += __shfl_xor(sum, m);
    if (l == 0) P[b * NC + c] = sum;
  }
}

// K2 sk1 (512 blocks): wave W -> (b = W>>8, o = W&255); u computed inline:
// u[c] = (t_arr[b][c]*Ss + P[b][c]) / 4096 (scale folded after reduce);
// u1[b][o] = relu(dot(sk_w1[o], u)).
__global__ __launch_bounds__(256) void k2_sk1(
    const float* __restrict__ t_arr, const float* __restrict__ P,
    const float* __restrict__ Ssum, const float* __restrict__ sk_w1,
    float* __restrict__ u1) {
  const int l = threadIdx.x & 63;
  const int W = blockIdx.x * 4 + (threadIdx.x >> 6);
  const int b = W >> 8, o = W & 255;
  const float Ss = Ssum[b];
  const float* wr = sk_w1 + (size_t)o * 512 + l * 8;
  float4 wa = *(const float4*)wr;
  float4 wb = *(const float4*)(wr + 4);
  const float* tr = t_arr + b * NC + l * 8;
  const float* pr = P + b * NC + l * 8;
  float4 ta = *(const float4*)tr, tb = *(const float4*)(tr + 4);
  float4 Pa = *(const float4*)pr, Pb = *(const float4*)(pr + 4);
  float4 ua, ub;
  ua.x = ta.x * Ss + Pa.x; ua.y = ta.y * Ss + Pa.y;
  ua.z = ta.z * Ss + Pa.z; ua.w = ta.w * Ss + Pa.w;
  ub.x = tb.x * Ss + Pb.x; ub.y = tb.y * Ss + Pb.y;
  ub.z = tb.z * Ss + Pb.z; ub.w = tb.w * Ss + Pb.w;
  float p = wa.x * ua.x + wa.y * ua.y + wa.z * ua.z + wa.w * ua.w +
            wb.x * ub.x + wb.y * ub.y + wb.z * ub.z + wb.w * ub.w;
  p = wave_reduce(p) * (1.0f / 4096.0f);
  if (l == 0) u1[b * 256 + o] = fmaxf(p, 0.0f);
}

// K2 sk2 (1024 blocks): wave W -> (b = W>>9, o = W&511):
// u2[b][o] = relu(dot(sk_w2[o], u1[b])).
__global__ __launch_bounds__(256) void k2_sk2(
    const float* __restrict__ u1, const float* __restrict__ sk_w2,
    float* __restrict__ u2) {
  const int l = threadIdx.x & 63;
  const int W = blockIdx.x * 4 + (threadIdx.x >> 6);
  const int b = W >> 9, o = W & 511;
  float4 wv = ((const float4*)(sk_w2 + (size_t)o * 256))[l];
  float4 cv = ((const float4*)(u1 + b * 256))[l];
  float p = wv.x * cv.x + wv.y * cv.y + wv.z * cv.z + wv.w * cv.w;
  p = wave_reduce(p);
  if (l == 0) u2[b * NC + o] = fmaxf(p, 0.0f);
}

// K3 v5: r6's proven GEMM+epilogue (43 µs), plus inline softmax+coef
// (replaces k2_smx): each block recomputes M,Z from u2 (256-thread reduces,
// bitwise identical to k2_smx) and builds its 128-row coef table in 2KB of
// dedicated LDS beyond the 32KB staging region.
__global__ __launch_bounds__(256, 4) void k3_gemm_epilogue(
    const unsigned short* __restrict__ wbfS, const unsigned short* __restrict__ xTS,
    const float* __restrict__ x, const float* __restrict__ s,
    const float* __restrict__ u2, const float* __restrict__ t_arr,
    const float* __restrict__ P, const float* __restrict__ Ssum,
    float* __restrict__ out) {
  __shared__ __align__(16) char smem[34816];  // 32KB stage dbuf + 2KB coef
  __shared__ float red4[4];
  const int t = threadIdx.x;
  const int bx = blockIdx.x, mz = blockIdx.y, b = blockIdx.z;
  const int w = t >> 6, l = t & 63;
  const int wm = w >> 1, wn = w & 1;
  const int l16 = l & 15, quad = l >> 4;

  // ---- inline softmax + coef table for this block's 128 rows ----
  float4* cf_l = (float4*)(smem + 32768);
  {
    const float Ss = Ssum[b];
    float v0 = u2[b * NC + t], v1 = u2[b * NC + t + 256];
    float M = block_reduce_max(fmaxf(v0, v1), red4);
    float e0 = __expf(v0 - M), e1 = __expf(v1 - M);
    float Z = block_reduce_sum(e0 + e1, red4);
    float inv = 1.0f / Z;
    if (t < 128) {
      const int o = mz * 128 + t;
      float a = __expf(u2[b * NC + o] - M) * inv;
      float tc = t_arr[b * NC + o];
      float Pv = P[b * NC + o];
      float c1 = a * tc;
      float c2v = 1.0f - a;
      float c3 = c1 * Ss + c2v * Pv;
      float4 cf = {c1, c2v, c3, tc};
      cf_l[t] = cf;
    }
  }

  f32x4 acc[4][4];
#pragma unroll
  for (int mi = 0; mi < 4; mi++)
#pragma unroll
    for (int ni = 0; ni < 4; ni++) {
      f32x4 z = {0.f, 0.f, 0.f, 0.f};
      acc[mi][ni] = z;
    }

  const char* gA0 = (const char*)wbfS + ((size_t)(mz * 8 + 2 * w) * 16) * 1024 + l * 16;
  const char* gA1 = gA0 + 16 * 1024;
  const char* gB0 = (const char*)xTS + ((size_t)(b * 256 + bx * 8 + 2 * w) * 16) * 1024 + l * 16;
  const char* gB1 = gB0 + 16 * 1024;
  char* lA0 = smem + (2 * w) * 1024;
  char* lA1 = smem + (2 * w + 1) * 1024;
  char* lB0 = smem + 8192 + (2 * w) * 1024;
  char* lB1 = smem + 8192 + (2 * w + 1) * 1024;
  const char* pA = smem + wm * 4096 + l * 16;
  const char* pB = smem + 8192 + wn * 4096 + l * 16;

#define K3_STAGE(buf, kk) do {                                  \
    gload16(gA0 + (kk) * 1024, lA0 + (buf) * 16384);            \
    gload16(gA1 + (kk) * 1024, lA1 + (buf) * 16384);            \
    gload16(gB0 + (kk) * 1024, lB0 + (buf) * 16384);            \
    gload16(gB1 + (kk) * 1024, lB1 + (buf) * 16384);            \
  } while (0)

#define K3_COMPUTE(buf) do {                                    \
    short8 af[4], bfr[4];                                       \
    _Pragma("unroll")                                           \
    for (int mi = 0; mi < 4; mi++)                              \
      af[mi] = *(const short8*)(pA + (buf) * 16384 + mi * 1024);\
    _Pragma("unroll")                                           \
    for (int ni = 0; ni < 4; ni++)                              \
      bfr[ni] = *(const short8*)(pB + (buf) * 16384 + ni * 1024);\
    _Pragma("unroll")                                           \
    for (int mi = 0; mi < 4; mi++)                              \
      _Pragma("unroll")                                         \
      for (int ni = 0; ni < 4; ni++)                            \
        acc[mi][ni] = __builtin_amdgcn_mfma_f32_16x16x32_bf16(  \
            af[mi], bfr[ni], acc[mi][ni], 0, 0, 0);             \
  } while (0)

  K3_STAGE(0, 0);
  __syncthreads();
#pragma unroll
  for (int kk = 0; kk < 16; kk += 2) {
    K3_STAGE(1, kk + 1);   // async loads in flight across the compute
    K3_COMPUTE(0);
    __syncthreads();       // drains vmcnt(0): buf1 ready
    if (kk + 2 < 16) K3_STAGE(0, kk + 2);
    K3_COMPUTE(1);
    __syncthreads();       // buf0 ready (and final: LDS free for epilogue)
  }

  // Epilogue: per-wave LDS transpose (wave-synchronous), 16-row chunks.
  float* eb = (float*)smem + w * 1088;  // 16 x 68 floats per wave
  const int row = l >> 2, cb = (l & 3) * 16;
  const int colb = bx * 128 + wn * 64 + cb;
  const float* sp = s + b * HW + colb;
  float4 sv[4];
#pragma unroll
  for (int j = 0; j < 4; j++) sv[j] = *(const float4*)(sp + 4 * j);
#pragma unroll
  for (int mi = 0; mi < 4; mi++) {
#pragma unroll
    for (int ni = 0; ni < 4; ni++)
#pragma unroll
      for (int r = 0; r < 4; r++)
        eb[(quad * 4 + r) * 68 + ni * 16 + l16] = acc[mi][ni][r];
    const int o = mz * 128 + wm * 64 + mi * 16 + row;
    float4 cf = cf_l[wm * 64 + mi * 16 + row];
    const size_t rbase = (size_t)(b * NC + o) * HW + colb;
#pragma unroll
    for (int j = 0; j < 4; j++) {
      f32x4 y = *(f32x4*)&eb[row * 68 + cb + 4 * j];
      float4 svj = sv[j];
      float4 xv = *(const float4*)(x + rbase + 4 * j);
      float4 ov;
      ov.x = xv.x * (cf.x * svj.x + cf.y * floorf((svj.x + cf.w) * 0.5f)) + cf.z + y.x;
      ov.y = xv.y * (cf.x * svj.y + cf.y * floorf((svj.y + cf.w) * 0.5f)) + cf.z + y.y;
      ov.z = xv.z * (cf.x * svj.z + cf.y * floorf((svj.z + cf.w) * 0.5f)) + cf.z + y.z;
      ov.w = xv.w * (cf.x * svj.w + cf.y * floorf((svj.w + cf.w) * 0.5f)) + cf.z + y.w;
      *(float4*)(out + rbase + 4 * j) = ov;
    }
  }
#undef K3_STAGE
#undef K3_COMPUTE
}

extern "C" void kernel_launch(void* const* d_in, const int* in_sizes, int n_in,
                              void* d_out, int out_size, void* d_ws, size_t ws_size,
                              hipStream_t stream) {
  const float* x       = (const float*)d_in[0];
  const float* w_b1    = (const float*)d_in[1];
  const float* b_b1    = (const float*)d_in[2];
  const float* w_b2    = (const float*)d_in[3];
  const float* b_b2    = (const float*)d_in[4];
  const float* w_conv1 = (const float*)d_in[5];
  const float* ln_g    = (const float*)d_in[6];
  const float* ln_b    = (const float*)d_in[7];
  const float* sk_w1   = (const float*)d_in[8];
  const float* sk_w2   = (const float*)d_in[9];
  const float* res_w   = (const float*)d_in[10];
  float* out = (float*)d_out;
  char* ws = (char*)d_ws;

  float* g_sum = (float*)(ws + 0x00000);          // 16 KB  (atomic)
  float* spat  = (float*)(ws + 0x08000);          // 128 KB (atomic)
  float* Ssum  = (float*)(ws + 0x28000);          // 32 B   (atomic)
  float* t_arr = (float*)(ws + 0x29000);          // 16 KB
  float* P     = (float*)(ws + 0x30000);          // 16 KB
  float* s     = (float*)(ws + 0x50000);          // 128 KB
  float* ca1   = (float*)(ws + 0x70000);          // 8 KB
  float* u1    = (float*)(ws + 0x72000);          // 8 KB
  float* ca2   = (float*)(ws + 0x74000);          // 16 KB
  float* u2    = (float*)(ws + 0x78000);          // 16 KB
  unsigned short* wbfS = (unsigned short*)(ws + 0x80000);   // 512 KB
  unsigned short* xTS  = (unsigned short*)(ws + 0x100000);  // 32 MB

  hipMemsetAsync(ws, 0, 0x28040, stream);  // zero g_sum, spat, Ssum
  k1_stats_transpose<<<dim3(64, 8, 8), 256, 0, stream>>>(x, w_conv1, res_w, g_sum, spat, xTS, wbfS);
  k2_mv1<<<512, 256, 0, stream>>>(g_sum, spat, w_b1, b_b1, s, Ssum, ca1);
  k2_mv2<<<1024, 256, 0, stream>>>(ca1, w_b2, b_b2, ca2);
  k2b_floorsum_ln<<<dim3(32, 8), 256, 0, stream>>>(s, ca2, ln_g, ln_b, t_arr, P);
  k2_sk1<<<512, 256, 0, stream>>>(t_arr, P, Ssum, sk_w1, u1);
  k2_sk2<<<1024, 256, 0, stream>>>(u1, sk_w2, u2);
  k3_gemm_epilogue<<<dim3(32, 4, 8), 256, 0, stream>>>(wbfS, xTS, x, s, u2, t_arr, P, Ssum, out);
}